// Round 1
// baseline (513.900 us; speedup 1.0000x reference)
//
#include <hip/hip_runtime.h>
#include <math.h>

#define PI_F 3.14159265358979323846f

__device__ __forceinline__ float gelu_f(float x){ return 0.5f*x*(1.0f+erff(x*0.7071067811865475f)); }
__device__ __forceinline__ float sigm_f(float x){ return 1.0f/(1.0f+expf(-x)); }

// B=8, H=W=64, HW=4096, NP=32768, FC=768, RC=8, P=8, K=9

// ---------------- K0: build prototype bank + proto_delta -> kern[8][81] ----------------
__global__ void k_bank(const float* __restrict__ pd, float* __restrict__ kern){
    int p = blockIdx.x, t = threadIdx.x;
    __shared__ float ridge[81];
    __shared__ float red[2];
    if (t < 81){
        int i = t/9, j = t%9;
        float ay = -1.0f + 0.25f*(float)i;   // yy = axis[i]
        float ax = -1.0f + 0.25f*(float)j;   // xx = axis[j]
        float ang = 2.0f*PI_F*(float)p/8.0f;
        const float Ls[3] = {0.45f,0.75f,1.05f};
        const float Ws[3] = {0.14f,0.20f,0.28f};
        float L = Ls[p%3], Wd = Ws[(p/3)%3];
        float cs = cosf(ang), sn = sinf(ang);
        float xr = ax*cs + ay*sn;
        float yr = -ax*sn + ay*cs;
        float tp = 1.0f - fminf(fabsf(xr)/L, 1.0f);
        float taper = powf(tp, 1.5f);
        float core = expf(-0.5f*((xr/L)*(xr/L)+(yr/Wd)*(yr/Wd)));
        float rr = taper*core*fmaxf(1.0f-(yr/Wd)*(yr/Wd), 0.0f);
        ridge[t] = rr;
    }
    __syncthreads();
    if (t==0){
        float m=0.f; for(int i=0;i<81;i++) m+=ridge[i]; m*=(1.0f/81.0f);
        float sa=0.f; for(int i=0;i<81;i++) sa+=fabsf(ridge[i]-m);
        red[0]=m; red[1]=fmaxf(sa,1e-6f);
    }
    __syncthreads();
    if (t<81){
        float kv = (ridge[t]-red[0])/red[1];
        kern[p*81+t] = kv + 0.05f*pd[p*81+t];
    }
}

// ---------------- K1: fp1 1x1 conv 768->8, channel-split partials ----------------
// grid (32 pixel-chunks, 8 channel-groups) x 256 threads; float4 per thread
__global__ void k_conv1(const float* __restrict__ fm, const float* __restrict__ w1,
                        float* __restrict__ part){
    int chunk = blockIdx.x;   // 0..31  (1024 px each)
    int g = blockIdx.y;       // 0..7   (96 channels each)
    int tid = threadIdx.x;
    __shared__ float wl[96][8];
    for (int i=tid;i<96*8;i+=256){ int c=i>>3, co=i&7; wl[c][co]=w1[co*768 + g*96 + c]; }
    __syncthreads();
    int b = chunk>>2;
    int q0 = ((chunk&3)<<8) + tid;   // float4 offset within batch plane (0..1023)
    const float4* fm4 = (const float4*)fm;
    float4 acc[8];
    #pragma unroll
    for(int co=0;co<8;co++) acc[co]=make_float4(0.f,0.f,0.f,0.f);
    int basec = b*768 + g*96;
    for(int c=0;c<96;c++){
        float4 x = fm4[(size_t)(basec+c)*1024 + q0];
        #pragma unroll
        for(int co=0;co<8;co++){
            float wv = wl[c][co];
            acc[co].x += wv*x.x; acc[co].y += wv*x.y; acc[co].z += wv*x.z; acc[co].w += wv*x.w;
        }
    }
    float4* p4 = (float4*)part;
    int gq = (b<<10) + q0;   // global f4 pixel index (0..8191)
    #pragma unroll
    for(int co=0;co<8;co++) p4[(size_t)(g*8+co)*8192 + gq] = acc[co];
}

// ---------------- K2: sum partials + bias + gelu -> t1[B][8][4096] ----------------
__global__ void k_comb1(const float* __restrict__ part, const float* __restrict__ b1,
                        float* __restrict__ t1){
    int i = blockIdx.x*256 + threadIdx.x;   // 0..65535 (f4 units)
    int co = i>>13, q = i&8191;
    const float4* p4 = (const float4*)part;
    float4 s = p4[(size_t)co*8192 + q];
    #pragma unroll
    for(int g=1;g<8;g++){
        float4 v = p4[(size_t)(g*8+co)*8192 + q];
        s.x+=v.x; s.y+=v.y; s.z+=v.z; s.w+=v.w;
    }
    float bb = b1[co];
    s.x = gelu_f(s.x+bb); s.y = gelu_f(s.y+bb); s.z = gelu_f(s.z+bb); s.w = gelu_f(s.w+bb);
    int b = q>>10, pq = q&1023;
    ((float4*)t1)[(size_t)(((b<<3)+co)<<10) + pq] = s;
}

// ---------------- K3: fp2 3x3 conv 8->8 + gelu; also channel mean and |.| mean ----------------
__global__ void k_conv2(const float* __restrict__ t1, const float* __restrict__ w2,
                        const float* __restrict__ b2, float* __restrict__ carrier,
                        float* __restrict__ cm, float* __restrict__ absc){
    __shared__ float wl[576];
    __shared__ float bl[8];
    int tid = threadIdx.x;
    for(int i=tid;i<576;i+=256) wl[i]=w2[i];
    if (tid<8) bl[tid]=b2[tid];
    __syncthreads();
    int gp = blockIdx.x*256 + tid;
    int b = gp>>12, p = gp&4095, y = p>>6, x = p&63;
    float acc[8];
    #pragma unroll
    for(int co=0;co<8;co++) acc[co]=bl[co];
    for(int ci=0;ci<8;ci++){
        const float* base = t1 + ((size_t)((b<<3)+ci)<<12);
        #pragma unroll
        for(int dy=-1;dy<=1;dy++){
            int yy=y+dy;
            #pragma unroll
            for(int dx=-1;dx<=1;dx++){
                int xx=x+dx;
                float v = (yy>=0 && yy<64 && xx>=0 && xx<64) ? base[(yy<<6)+xx] : 0.f;
                int ti = (dy+1)*3+(dx+1);
                #pragma unroll
                for(int co=0;co<8;co++) acc[co] += v*wl[(co*8+ci)*9+ti];
            }
        }
    }
    float s=0.f, sa=0.f;
    #pragma unroll
    for(int co=0;co<8;co++){
        float cv = gelu_f(acc[co]);
        carrier[((size_t)((b<<3)+co)<<12)+p] = cv;
        s += cv; sa += fabsf(cv);
    }
    cm[gp] = s*(1.0f/8.0f);
    absc[gp] = sa*(1.0f/8.0f);
}

// ---------------- K4: carrier_hp = cm - avg3(cm) ----------------
__global__ void k_chp(const float* __restrict__ cm, float* __restrict__ chp){
    int gp = blockIdx.x*256+threadIdx.x;
    int b=gp>>12, p=gp&4095, y=p>>6, x=p&63;
    const float* base = cm + (b<<12);
    float s=0.f;
    for(int dy=-1;dy<=1;dy++){
        int yy=y+dy; if(yy<0||yy>=64) continue;
        for(int dx=-1;dx<=1;dx++){
            int xx=x+dx; if(xx<0||xx>=64) continue;
            s += base[(yy<<6)+xx];
        }
    }
    chp[gp] = base[p] - s*(1.0f/9.0f);
}

// ---------------- K5: 9x9 bank conv -> responses[8]; also csraw=avg3(|chp|) ----------------
__global__ void k_resp(const float* __restrict__ chp, const float* __restrict__ kern,
                       float* __restrict__ resp, float* __restrict__ csraw){
    __shared__ float kl[648];
    int tid=threadIdx.x;
    for(int i=tid;i<648;i+=256) kl[i]=kern[i];
    __syncthreads();
    int gp = blockIdx.x*256+tid;
    int b=gp>>12, p=gp&4095, y=p>>6, x=p&63;
    const float* base = chp + (b<<12);
    float acc[8];
    #pragma unroll
    for(int q=0;q<8;q++) acc[q]=0.f;
    float cs=0.f;
    for(int dy=-4;dy<=4;dy++){
        int yy=y+dy;
        for(int dx=-4;dx<=4;dx++){
            int xx=x+dx;
            float v = (yy>=0&&yy<64&&xx>=0&&xx<64)?base[(yy<<6)+xx]:0.f;
            int ti=(dy+4)*9+(dx+4);
            #pragma unroll
            for(int q=0;q<8;q++) acc[q]+=v*kl[q*81+ti];
            if (dy>=-1&&dy<=1&&dx>=-1&&dx<=1) cs += fabsf(v);
        }
    }
    #pragma unroll
    for(int q=0;q<8;q++) resp[((size_t)((b<<3)+q)<<12)+p]=acc[q];
    csraw[gp]=cs*(1.0f/9.0f);
}

// ---------------- K6: per-batch reductions ----------------
// red[b*8+0]=den, +1=cs_min, +2=cs_max, +3=dens_min, +4=dens_max
__global__ void k_reduce(const float* __restrict__ csraw, const float* __restrict__ absc,
                         float* __restrict__ red){
    __shared__ float s0[256], s1[256], s2[256], s3[256], s4[256];
    int b=blockIdx.x, tid=threadIdx.x;
    float sm=0.f, cmn=1e30f, cmx=-1e30f, amn=1e30f, amx=-1e30f;
    for(int k=0;k<16;k++){
        int p = tid + k*256;
        float cv = csraw[(b<<12)+p], av = absc[(b<<12)+p];
        sm+=av;
        cmn=fminf(cmn,cv); cmx=fmaxf(cmx,cv);
        amn=fminf(amn,av); amx=fmaxf(amx,av);
    }
    s0[tid]=sm; s1[tid]=cmn; s2[tid]=cmx; s3[tid]=amn; s4[tid]=amx;
    __syncthreads();
    for(int st=128;st>0;st>>=1){
        if(tid<st){
            s0[tid]+=s0[tid+st];
            s1[tid]=fminf(s1[tid],s1[tid+st]);
            s2[tid]=fmaxf(s2[tid],s2[tid+st]);
            s3[tid]=fminf(s3[tid],s3[tid+st]);
            s4[tid]=fmaxf(s4[tid],s4[tid+st]);
        }
        __syncthreads();
    }
    if(tid==0){
        float den = fmaxf(s0[0]*(1.0f/4096.0f), 1e-6f);
        red[b*8+0]=den;
        red[b*8+1]=s1[0];
        red[b*8+2]=s2[0];
        red[b*8+3]=s3[0]/den;   // division is monotone: min/max commute with /den
        red[b*8+4]=s4[0]/den;
    }
}

// ---------------- K7: full gate pipeline per batch in LDS -> stroke_gate ----------------
__global__ void __launch_bounds__(1024) k_gate(const float* __restrict__ csraw,
    const float* __restrict__ absc, const float* __restrict__ objn,
    const float* __restrict__ alpha, const float* __restrict__ red,
    float* __restrict__ sg){
    __shared__ float A[4096], Bs[4096], Cs[4096];
    int b=blockIdx.x, tid=threadIdx.x;
    float den=red[b*8+0], cmn=red[b*8+1], cmx=red[b*8+2], dmn=red[b*8+3], dmx=red[b*8+4];
    float cinv = 1.0f/fmaxf(cmx-cmn,1e-6f);
    float dinv = 1.0f/fmaxf(dmx-dmn,1e-6f);
    // stage 1: A = ev, Bs = sigmoid((ev-THR)/TEMP)
    for(int k=0;k<4;k++){
        int p=tid+k*1024;
        float cs=(csraw[(b<<12)+p]-cmn)*cinv;
        float d = absc[(b<<12)+p]/den;
        float ds=(d-dmn)*dinv;
        float ev = 0.65f*cs + 0.35f*ds;
        A[p]=ev;
        Bs[p]=sigm_f((ev-0.2f)*(1.0f/0.08f));
    }
    __syncthreads();
    // stage 2: Cs = maxpool5(Bs)  (gate)
    for(int k=0;k<4;k++){
        int p=tid+k*1024; int y=p>>6,x=p&63;
        float m=-1e30f;
        for(int dy=-2;dy<=2;dy++){int yy=y+dy; if(yy<0||yy>=64)continue;
            for(int dx=-2;dx<=2;dx++){int xx=x+dx; if(xx<0||xx>=64)continue;
                m=fmaxf(m,Bs[(yy<<6)+xx]);}}
        Cs[p]=m;
    }
    __syncthreads();
    // stage 3: Bs = erode5(mask0),  mask0 = (ev >= THR)
    for(int k=0;k<4;k++){
        int p=tid+k*1024; int y=p>>6,x=p&63;
        float m=1.f;
        for(int dy=-2;dy<=2;dy++){int yy=y+dy; if(yy<0||yy>=64)continue;
            for(int dx=-2;dx<=2;dx++){int xx=x+dx; if(xx<0||xx>=64)continue;
                if (A[(yy<<6)+xx] < 0.2f) m=0.f;}}
        Bs[p]=m;
    }
    __syncthreads();
    // stage 4: A = maxpool5(Bs)  (opened)
    for(int k=0;k<4;k++){
        int p=tid+k*1024; int y=p>>6,x=p&63;
        float m=-1e30f;
        for(int dy=-2;dy<=2;dy++){int yy=y+dy; if(yy<0||yy>=64)continue;
            for(int dx=-2;dx<=2;dx++){int xx=x+dx; if(xx<0||xx>=64)continue;
                m=fmaxf(m,Bs[(yy<<6)+xx]);}}
        A[p]=m;
    }
    __syncthreads();
    // stage 5: Bs = maxpool5(A)  (final mask)
    for(int k=0;k<4;k++){
        int p=tid+k*1024; int y=p>>6,x=p&63;
        float m=-1e30f;
        for(int dy=-2;dy<=2;dy++){int yy=y+dy; if(yy<0||yy>=64)continue;
            for(int dx=-2;dx<=2;dx++){int xx=x+dx; if(xx<0||xx>=64)continue;
                m=fmaxf(m,A[(yy<<6)+xx]);}}
        Bs[p]=m;
    }
    __syncthreads();
    // stage 6: A = sigmoid(objectness)
    for(int k=0;k<4;k++){
        int p=tid+k*1024;
        A[p]=sigm_f(objn[(b<<12)+p]);
    }
    __syncthreads();
    // final: sg = sigmoid(alpha) * avg3(A) * (Cs*Bs) * (0.7+0.3*clip(dens,0,2))
    for(int k=0;k<4;k++){
        int p=tid+k*1024; int y=p>>6,x=p&63;
        float s=0.f;
        for(int dy=-1;dy<=1;dy++){int yy=y+dy; if(yy<0||yy>=64)continue;
            for(int dx=-1;dx<=1;dx++){int xx=x+dx; if(xx<0||xx>=64)continue;
                s += A[(yy<<6)+xx];}}
        float blob = s*(1.0f/9.0f);
        float gate = Cs[p]*Bs[p];
        float d = absc[(b<<12)+p]/den;
        float sgv = sigm_f(alpha[(b<<12)+p]) * blob * gate * (0.7f+0.3f*fminf(fmaxf(d,0.f),2.f));
        sg[(b<<12)+p] = sgv;
    }
}

// ---------------- K8: top-2 softmax over prototype bias; ss0 = sum(responses*pw) ----------------
__global__ void k_pw(const float* __restrict__ theta, const float* __restrict__ length,
    const float* __restrict__ width, const float* __restrict__ plog,
    const float* __restrict__ resp, float* __restrict__ ss0){
    int gp=blockIdx.x*256+threadIdx.x;
    int b=gp>>12, p=gp&4095;
    float ta = tanhf(theta[gp])*PI_F;
    float lv = sigm_f(length[gp])*0.85f+0.25f;
    float wv = sigm_f(width[gp])*0.22f+0.08f;
    const float Ls[3]={0.45f,0.75f,1.05f};
    const float Ws[3]={0.14f,0.20f,0.28f};
    float m1=-1e30f,m2=-1e30f; int i1=0,i2=0;
    #pragma unroll
    for(int q=0;q<8;q++){
        float ang = 2.0f*PI_F*(float)q/8.0f;
        float la=Ls[q%3], wa=Ws[(q/3)%3];
        float bias = plog[((size_t)((b<<3)+q)<<12)+p]
                   + 1.25f*cosf(ta-ang)
                   - (lv-la)*(lv-la)*(1.0f/0.08f)
                   - (wv-wa)*(wv-wa)*(1.0f/0.01f);
        if (bias>m1){m2=m1;i2=i1;m1=bias;i1=q;}
        else if (bias>m2){m2=bias;i2=q;}
    }
    float e2=expf(m2-m1);
    float inv=1.0f/(1.0f+e2);
    float r1=resp[((size_t)((b<<3)+i1)<<12)+p];
    float r2=resp[((size_t)((b<<3)+i2)<<12)+p];
    ss0[gp]=r1*inv + r2*e2*inv;
}

// ---------------- K9: ss final + feats + pm1 1x1 conv + gelu -> h[B][8][4096] ----------------
__global__ void k_h(const float* __restrict__ ss0, const float* __restrict__ sg,
    const float* __restrict__ theta, const float* __restrict__ curv,
    const float* __restrict__ carrier, const float* __restrict__ w3,
    const float* __restrict__ b3, float* __restrict__ h){
    __shared__ float wl[96]; __shared__ float bl[8];
    int tid=threadIdx.x;
    if(tid<96) wl[tid]=w3[tid];
    if(tid<8) bl[tid]=b3[tid];
    __syncthreads();
    int gp=blockIdx.x*256+tid;
    int b=gp>>12,p=gp&4095,y=p>>6,x=p&63;
    const float* base = ss0 + (b<<12);
    float s=0.f;
    for(int dy=-1;dy<=1;dy++){int yy=y+dy; if(yy<0||yy>=64)continue;
        for(int dx=-1;dx<=1;dx++){int xx=x+dx;if(xx<0||xx>=64)continue;
            s+=base[(yy<<6)+xx];}}
    float ss1 = base[p]-s*(1.0f/9.0f);
    float cu = tanhf(curv[gp]);
    float ssv = sg[gp]*ss1*(1.0f+0.15f*cu);
    float ta = tanhf(theta[gp])*PI_F;
    float dxv=cosf(ta), dyv=sinf(ta);
    float car[8];
    #pragma unroll
    for(int ci=0;ci<8;ci++) car[ci]=carrier[((size_t)((b<<3)+ci)<<12)+p];
    #pragma unroll
    for(int co=0;co<8;co++){
        const float* w=&wl[co*12];
        float t = w[8] + w[9]*dxv + w[10]*dyv + w[11]*cu;
        #pragma unroll
        for(int ci=0;ci<8;ci++) t += w[ci]*car[ci];
        h[((size_t)((b<<3)+co)<<12)+p] = gelu_f(bl[co] + ssv*t);
    }
}

// ---------------- K10: pm2 1x1 conv 8->768 -> out (100 MB write) ----------------
// grid (32 pixel-chunks, 16 co-groups) x 256 threads, 48 co per group, float4 px
__global__ void k_pm2(const float* __restrict__ h, const float* __restrict__ w4,
                      const float* __restrict__ b4, float* __restrict__ out){
    int chunk=blockIdx.x; // 0..31
    int cg=blockIdx.y;    // 0..15
    int tid=threadIdx.x;
    int b=chunk>>2;
    int q0=((chunk&3)<<8)+tid;  // f4 index within batch plane
    const float4* h4=(const float4*)h;
    float4 hv[8];
    #pragma unroll
    for(int ci=0;ci<8;ci++) hv[ci]=h4[((size_t)((b<<3)+ci)<<10)+q0];
    float4* o4=(float4*)out;
    for(int k=0;k<48;k++){
        int co=cg*48+k;
        float bb=b4[co];
        float4 o=make_float4(bb,bb,bb,bb);
        #pragma unroll
        for(int ci=0;ci<8;ci++){
            float wv=w4[co*8+ci];
            o.x+=wv*hv[ci].x; o.y+=wv*hv[ci].y; o.z+=wv*hv[ci].z; o.w+=wv*hv[ci].w;
        }
        o4[(size_t)(b*768+co)*1024 + q0]=o;
    }
}

extern "C" void kernel_launch(void* const* d_in, const int* in_sizes, int n_in,
                              void* d_out, int out_size, void* d_ws, size_t ws_size,
                              hipStream_t stream) {
    const float* fm     =(const float*)d_in[0];
    const float* theta  =(const float*)d_in[1];
    const float* length =(const float*)d_in[2];
    const float* width  =(const float*)d_in[3];
    const float* curv   =(const float*)d_in[4];
    const float* alpha  =(const float*)d_in[5];
    const float* objn   =(const float*)d_in[6];
    const float* plog   =(const float*)d_in[7];
    const float* fp1w   =(const float*)d_in[8];
    const float* fp1b   =(const float*)d_in[9];
    const float* fp2w   =(const float*)d_in[10];
    const float* fp2b   =(const float*)d_in[11];
    const float* pm1w   =(const float*)d_in[12];
    const float* pm1b   =(const float*)d_in[13];
    const float* pm2w   =(const float*)d_in[14];
    const float* pm2b   =(const float*)d_in[15];
    const float* pdelta =(const float*)d_in[16];

    float* ws=(float*)d_ws;
    float* kern    = ws;                 // 1024 (648 used)
    float* part    = kern + 1024;        // 8*8*32768 = 2097152
    float* t1      = part + 2097152;     // 262144
    float* carrier = t1 + 262144;        // 262144
    float* cm      = carrier + 262144;   // 32768
    float* absc    = cm + 32768;         // 32768
    float* chp     = absc + 32768;       // 32768
    float* csraw   = chp + 32768;        // 32768
    float* resp    = csraw + 32768;      // 262144
    float* red     = resp + 262144;      // 64
    float* sg      = red + 64;           // 32768
    float* ss0     = sg + 32768;         // 32768
    float* h       = ss0 + 32768;        // 262144
    float* out     = (float*)d_out;

    k_bank  <<<8, 128, 0, stream>>>(pdelta, kern);
    k_conv1 <<<dim3(32,8), 256, 0, stream>>>(fm, fp1w, part);
    k_comb1 <<<256, 256, 0, stream>>>(part, fp1b, t1);
    k_conv2 <<<128, 256, 0, stream>>>(t1, fp2w, fp2b, carrier, cm, absc);
    k_chp   <<<128, 256, 0, stream>>>(cm, chp);
    k_resp  <<<128, 256, 0, stream>>>(chp, kern, resp, csraw);
    k_reduce<<<8, 256, 0, stream>>>(csraw, absc, red);
    k_gate  <<<8, 1024, 0, stream>>>(csraw, absc, objn, alpha, red, sg);
    k_pw    <<<128, 256, 0, stream>>>(theta, length, width, plog, resp, ss0);
    k_h     <<<128, 256, 0, stream>>>(ss0, sg, theta, curv, carrier, pm1w, pm1b, h);
    k_pm2   <<<dim3(32,16), 256, 0, stream>>>(h, pm2w, pm2b, out);
}

// Round 2
// 398.962 us; speedup vs baseline: 1.2881x; 1.2881x over previous
//
#include <hip/hip_runtime.h>
#include <math.h>

#define PI_F 3.14159265358979323846f

__device__ __forceinline__ float gelu_f(float x){ return 0.5f*x*(1.0f+erff(x*0.7071067811865475f)); }
__device__ __forceinline__ float sigm_f(float x){ return 1.0f/(1.0f+expf(-x)); }

// B=8, H=W=64, HW=4096, NP=32768, FC=768, RC=8, P=8, K=9

// ---------------- K1: fp1 1x1 conv 768->8, channel-split partials ----------------
// grid (32 pixel-chunks, G channel-groups) x 256 threads; float4 per thread
__global__ void k_conv1(const float* __restrict__ fm, const float* __restrict__ w1,
                        float* __restrict__ part, int Cg){
    int chunk = blockIdx.x;   // 0..31  (256 f4 each)
    int g = blockIdx.y;       // 0..G-1 (Cg channels each)
    int tid = threadIdx.x;
    __shared__ float wl[96*8];
    for (int i=tid;i<Cg*8;i+=256){ int c=i>>3, co=i&7; wl[i]=w1[co*768 + g*Cg + c]; }
    __syncthreads();
    int b = chunk>>2;
    int q0 = ((chunk&3)<<8) + tid;   // float4 offset within batch plane (0..1023)
    const float4* fm4 = (const float4*)fm;
    float4 acc[8];
    #pragma unroll
    for(int co=0;co<8;co++) acc[co]=make_float4(0.f,0.f,0.f,0.f);
    int basec = b*768 + g*Cg;
    for(int c=0;c<Cg;c++){
        float4 x = fm4[(size_t)(basec+c)*1024 + q0];
        #pragma unroll
        for(int co=0;co<8;co++){
            float wv = wl[(c<<3)+co];
            acc[co].x += wv*x.x; acc[co].y += wv*x.y; acc[co].z += wv*x.z; acc[co].w += wv*x.w;
        }
    }
    float4* p4 = (float4*)part;
    int gq = (b<<10) + q0;   // global f4 pixel index (0..8191)
    #pragma unroll
    for(int co=0;co<8;co++) p4[(size_t)(g*8+co)*8192 + gq] = acc[co];
}

// ---------------- K2: sum partials + bias + gelu -> t1[B][8][4096] ----------------
__global__ void k_comb1(const float* __restrict__ part, const float* __restrict__ b1,
                        float* __restrict__ t1, int G){
    int i = blockIdx.x*256 + threadIdx.x;   // 0..65535 (f4 units)
    int co = i>>13, q = i&8191;
    const float4* p4 = (const float4*)part;
    float4 s = make_float4(0.f,0.f,0.f,0.f);
    for(int g=0;g<G;g++){
        float4 v = p4[(size_t)(g*8+co)*8192 + q];
        s.x+=v.x; s.y+=v.y; s.z+=v.z; s.w+=v.w;
    }
    float bb = b1[co];
    s.x = gelu_f(s.x+bb); s.y = gelu_f(s.y+bb); s.z = gelu_f(s.z+bb); s.w = gelu_f(s.w+bb);
    int b = q>>10, pq = q&1023;
    ((float4*)t1)[(size_t)(((b<<3)+co)<<10) + pq] = s;
}

// ---------------- K3: fp2 3x3 conv 8->8 + gelu; also channel mean and |.| mean ----------------
__global__ void k_conv2(const float* __restrict__ t1, const float* __restrict__ w2,
                        const float* __restrict__ b2, float* __restrict__ carrier,
                        float* __restrict__ cm, float* __restrict__ absc){
    __shared__ float wl[576];
    __shared__ float bl[8];
    int tid = threadIdx.x;
    for(int i=tid;i<576;i+=256) wl[i]=w2[i];
    if (tid<8) bl[tid]=b2[tid];
    __syncthreads();
    int gp = blockIdx.x*256 + tid;
    int b = gp>>12, p = gp&4095, y = p>>6, x = p&63;
    float acc[8];
    #pragma unroll
    for(int co=0;co<8;co++) acc[co]=bl[co];
    for(int ci=0;ci<8;ci++){
        const float* base = t1 + ((size_t)((b<<3)+ci)<<12);
        #pragma unroll
        for(int dy=-1;dy<=1;dy++){
            int yy=y+dy;
            #pragma unroll
            for(int dx=-1;dx<=1;dx++){
                int xx=x+dx;
                float v = (yy>=0 && yy<64 && xx>=0 && xx<64) ? base[(yy<<6)+xx] : 0.f;
                int ti = (dy+1)*3+(dx+1);
                #pragma unroll
                for(int co=0;co<8;co++) acc[co] += v*wl[(co*8+ci)*9+ti];
            }
        }
    }
    float s=0.f, sa=0.f;
    #pragma unroll
    for(int co=0;co<8;co++){
        float cv = gelu_f(acc[co]);
        carrier[((size_t)((b<<3)+co)<<12)+p] = cv;
        s += cv; sa += fabsf(cv);
    }
    cm[gp] = s*(1.0f/8.0f);
    absc[gp] = sa*(1.0f/8.0f);
}

// ---------------- K4 (fused): bank recompute + chp in LDS + 9x9 conv + top2-softmax ----------------
// grid 128 x 256. block (b, band): 4 rows of one batch plane.
__global__ void k_resp(const float* __restrict__ cm, const float* __restrict__ pd,
                       const float* __restrict__ theta, const float* __restrict__ length,
                       const float* __restrict__ width, const float* __restrict__ plog,
                       float* __restrict__ ss0, float* __restrict__ csraw){
    __shared__ float cmT[14*64];    // rows y0-5 .. y0+8 (zero outside image)
    __shared__ float chpT[12*64];   // rows y0-4 .. y0+7 (zero outside image)
    __shared__ float ridge[648];
    __shared__ float kl[648];
    __shared__ float pmS[8], pdenS[8];
    int tid = threadIdx.x;
    int blk = blockIdx.x;
    int b = blk>>4, band = blk&15, y0 = band<<2;

    // load cm tile
    for(int i=tid;i<896;i+=256){
        int r=i>>6, x=i&63;
        int gy=y0-5+r;
        cmT[i] = (gy>=0&&gy<64) ? cm[(b<<12)+(gy<<6)+x] : 0.f;
    }
    // recompute prototype ridge bank (per block; cheap)
    for(int t=tid;t<648;t+=256){
        int p=t/81, idx=t-p*81;
        int i=idx/9, j=idx-i*9;
        float ay=-1.f+0.25f*(float)i;
        float ax=-1.f+0.25f*(float)j;
        float ang=2.f*PI_F*(float)p*0.125f;
        const float Ls[3]={0.45f,0.75f,1.05f};
        const float Ws[3]={0.14f,0.20f,0.28f};
        float L=Ls[p%3], Wd=Ws[(p/3)%3];
        float cs=cosf(ang), sn=sinf(ang);
        float xr=ax*cs+ay*sn;
        float yr=-ax*sn+ay*cs;
        float tp=1.f-fminf(fabsf(xr)/L,1.f);
        float taper=powf(tp,1.5f);
        float core=expf(-0.5f*((xr/L)*(xr/L)+(yr/Wd)*(yr/Wd)));
        ridge[t]=taper*core*fmaxf(1.f-(yr/Wd)*(yr/Wd),0.f);
    }
    __syncthreads();
    // chp tile (uses cmT) ; zero-pad semantics of avg3 match reference
    for(int i=tid;i<768;i+=256){
        int r=i>>6, x=i&63;
        int gy=y0-4+r;
        float v=0.f;
        if (gy>=0&&gy<64){
            float s=0.f;
            #pragma unroll
            for(int dy=-1;dy<=1;dy++){
                int lr=r+1+dy;
                #pragma unroll
                for(int dx=-1;dx<=1;dx++){
                    int xx=x+dx;
                    if(xx>=0&&xx<64) s+=cmT[(lr<<6)+xx];
                }
            }
            v=cmT[((r+1)<<6)+x]-s*(1.f/9.f);
        }
        chpT[i]=v;
    }
    // bank mean: 32 lanes per prototype
    {
        int p=tid>>5, k=tid&31;
        float s=0.f;
        for(int e=k;e<81;e+=32) s+=ridge[p*81+e];
        for(int off=16;off>0;off>>=1) s+=__shfl_down(s,off,32);
        if(k==0) pmS[p]=s*(1.f/81.f);
    }
    __syncthreads();
    {
        int p=tid>>5, k=tid&31;
        float m=pmS[p];
        float s=0.f;
        for(int e=k;e<81;e+=32) s+=fabsf(ridge[p*81+e]-m);
        for(int off=16;off>0;off>>=1) s+=__shfl_down(s,off,32);
        if(k==0) pdenS[p]=fmaxf(s,1e-6f);
    }
    __syncthreads();
    for(int t=tid;t<648;t+=256){
        int p=t/81;
        kl[t]=(ridge[t]-pmS[p])/pdenS[p]+0.05f*pd[t];
    }
    __syncthreads();

    // 9x9 conv from LDS; wave-uniform row -> stride-1 LDS (conflict-free), kl reads broadcast
    int ly=tid>>6, x=tid&63;
    int gy=y0+ly;
    int gp=(b<<12)+(gy<<6)+x;
    float acc[8];
    #pragma unroll
    for(int q=0;q<8;q++) acc[q]=0.f;
    float cs=0.f;
    for(int dy=-4;dy<=4;dy++){
        int lr=ly+dy+4;
        for(int dx=-4;dx<=4;dx++){
            int xx=x+dx;
            float v=(xx>=0&&xx<64)?chpT[(lr<<6)+xx]:0.f;
            int ti=(dy+4)*9+(dx+4);
            #pragma unroll
            for(int q=0;q<8;q++) acc[q]+=v*kl[q*81+ti];
            if(dy>=-1&&dy<=1&&dx>=-1&&dx<=1) cs+=fabsf(v);
        }
    }
    csraw[gp]=cs*(1.f/9.f);

    // top-2 softmax over prototype bias, using in-register responses
    float ta=tanhf(theta[gp])*PI_F;
    float lv=sigm_f(length[gp])*0.85f+0.25f;
    float wv=sigm_f(width[gp])*0.22f+0.08f;
    const float Ls[3]={0.45f,0.75f,1.05f};
    const float Ws[3]={0.14f,0.20f,0.28f};
    int pp=(gy<<6)+x;
    float m1=-1e30f,m2=-1e30f; float r1=0.f,r2=0.f;
    #pragma unroll
    for(int q=0;q<8;q++){
        float ang=2.f*PI_F*(float)q*0.125f;
        float la=Ls[q%3], wa=Ws[(q/3)%3];
        float bias=plog[((size_t)((b<<3)+q)<<12)+pp]
                 +1.25f*cosf(ta-ang)
                 -(lv-la)*(lv-la)*(1.f/0.08f)
                 -(wv-wa)*(wv-wa)*(1.f/0.01f);
        if(bias>m1){m2=m1;r2=r1;m1=bias;r1=acc[q];}
        else if(bias>m2){m2=bias;r2=acc[q];}
    }
    float e2=expf(m2-m1);
    float inv=1.0f/(1.0f+e2);
    ss0[gp]=r1*inv + r2*e2*inv;
}

// ---------------- K5: per-batch reductions ----------------
__global__ void k_reduce(const float* __restrict__ csraw, const float* __restrict__ absc,
                         float* __restrict__ red){
    __shared__ float s0[256], s1[256], s2[256], s3[256], s4[256];
    int b=blockIdx.x, tid=threadIdx.x;
    float sm=0.f, cmn=1e30f, cmx=-1e30f, amn=1e30f, amx=-1e30f;
    for(int k=0;k<16;k++){
        int p = tid + k*256;
        float cv = csraw[(b<<12)+p], av = absc[(b<<12)+p];
        sm+=av;
        cmn=fminf(cmn,cv); cmx=fmaxf(cmx,cv);
        amn=fminf(amn,av); amx=fmaxf(amx,av);
    }
    s0[tid]=sm; s1[tid]=cmn; s2[tid]=cmx; s3[tid]=amn; s4[tid]=amx;
    __syncthreads();
    for(int st=128;st>0;st>>=1){
        if(tid<st){
            s0[tid]+=s0[tid+st];
            s1[tid]=fminf(s1[tid],s1[tid+st]);
            s2[tid]=fmaxf(s2[tid],s2[tid+st]);
            s3[tid]=fminf(s3[tid],s3[tid+st]);
            s4[tid]=fmaxf(s4[tid],s4[tid+st]);
        }
        __syncthreads();
    }
    if(tid==0){
        float den = fmaxf(s0[0]*(1.0f/4096.0f), 1e-6f);
        red[b*8+0]=den;
        red[b*8+1]=s1[0];
        red[b*8+2]=s2[0];
        red[b*8+3]=s3[0]/den;   // division is monotone: min/max commute with /den
        red[b*8+4]=s4[0]/den;
    }
}

// ---------------- K6: full gate pipeline per batch in LDS -> stroke_gate ----------------
__global__ void __launch_bounds__(1024) k_gate(const float* __restrict__ csraw,
    const float* __restrict__ absc, const float* __restrict__ objn,
    const float* __restrict__ alpha, const float* __restrict__ red,
    float* __restrict__ sg){
    __shared__ float A[4096], Bs[4096], Cs[4096];
    int b=blockIdx.x, tid=threadIdx.x;
    float den=red[b*8+0], cmn=red[b*8+1], cmx=red[b*8+2], dmn=red[b*8+3], dmx=red[b*8+4];
    float cinv = 1.0f/fmaxf(cmx-cmn,1e-6f);
    float dinv = 1.0f/fmaxf(dmx-dmn,1e-6f);
    for(int k=0;k<4;k++){
        int p=tid+k*1024;
        float cs=(csraw[(b<<12)+p]-cmn)*cinv;
        float d = absc[(b<<12)+p]/den;
        float ds=(d-dmn)*dinv;
        float ev = 0.65f*cs + 0.35f*ds;
        A[p]=ev;
        Bs[p]=sigm_f((ev-0.2f)*(1.0f/0.08f));
    }
    __syncthreads();
    for(int k=0;k<4;k++){
        int p=tid+k*1024; int y=p>>6,x=p&63;
        float m=-1e30f;
        for(int dy=-2;dy<=2;dy++){int yy=y+dy; if(yy<0||yy>=64)continue;
            for(int dx=-2;dx<=2;dx++){int xx=x+dx; if(xx<0||xx>=64)continue;
                m=fmaxf(m,Bs[(yy<<6)+xx]);}}
        Cs[p]=m;
    }
    __syncthreads();
    for(int k=0;k<4;k++){
        int p=tid+k*1024; int y=p>>6,x=p&63;
        float m=1.f;
        for(int dy=-2;dy<=2;dy++){int yy=y+dy; if(yy<0||yy>=64)continue;
            for(int dx=-2;dx<=2;dx++){int xx=x+dx; if(xx<0||xx>=64)continue;
                if (A[(yy<<6)+xx] < 0.2f) m=0.f;}}
        Bs[p]=m;
    }
    __syncthreads();
    for(int k=0;k<4;k++){
        int p=tid+k*1024; int y=p>>6,x=p&63;
        float m=-1e30f;
        for(int dy=-2;dy<=2;dy++){int yy=y+dy; if(yy<0||yy>=64)continue;
            for(int dx=-2;dx<=2;dx++){int xx=x+dx; if(xx<0||xx>=64)continue;
                m=fmaxf(m,Bs[(yy<<6)+xx]);}}
        A[p]=m;
    }
    __syncthreads();
    for(int k=0;k<4;k++){
        int p=tid+k*1024; int y=p>>6,x=p&63;
        float m=-1e30f;
        for(int dy=-2;dy<=2;dy++){int yy=y+dy; if(yy<0||yy>=64)continue;
            for(int dx=-2;dx<=2;dx++){int xx=x+dx; if(xx<0||xx>=64)continue;
                m=fmaxf(m,A[(yy<<6)+xx]);}}
        Bs[p]=m;
    }
    __syncthreads();
    for(int k=0;k<4;k++){
        int p=tid+k*1024;
        A[p]=sigm_f(objn[(b<<12)+p]);
    }
    __syncthreads();
    for(int k=0;k<4;k++){
        int p=tid+k*1024; int y=p>>6,x=p&63;
        float s=0.f;
        for(int dy=-1;dy<=1;dy++){int yy=y+dy; if(yy<0||yy>=64)continue;
            for(int dx=-1;dx<=1;dx++){int xx=x+dx; if(xx<0||xx>=64)continue;
                s += A[(yy<<6)+xx];}}
        float blob = s*(1.0f/9.0f);
        float gate = Cs[p]*Bs[p];
        float d = absc[(b<<12)+p]/den;
        float sgv = sigm_f(alpha[(b<<12)+p]) * blob * gate * (0.7f+0.3f*fminf(fmaxf(d,0.f),2.f));
        sg[(b<<12)+p] = sgv;
    }
}

// ---------------- K7: ss final + feats + pm1 1x1 conv + gelu -> h[B][8][4096] ----------------
__global__ void k_h(const float* __restrict__ ss0, const float* __restrict__ sg,
    const float* __restrict__ theta, const float* __restrict__ curv,
    const float* __restrict__ carrier, const float* __restrict__ w3,
    const float* __restrict__ b3, float* __restrict__ h){
    __shared__ float wl[96]; __shared__ float bl[8];
    int tid=threadIdx.x;
    if(tid<96) wl[tid]=w3[tid];
    if(tid<8) bl[tid]=b3[tid];
    __syncthreads();
    int gp=blockIdx.x*256+tid;
    int b=gp>>12,p=gp&4095,y=p>>6,x=p&63;
    const float* base = ss0 + (b<<12);
    float s=0.f;
    for(int dy=-1;dy<=1;dy++){int yy=y+dy; if(yy<0||yy>=64)continue;
        for(int dx=-1;dx<=1;dx++){int xx=x+dx;if(xx<0||xx>=64)continue;
            s+=base[(yy<<6)+xx];}}
    float ss1 = base[p]-s*(1.0f/9.0f);
    float cu = tanhf(curv[gp]);
    float ssv = sg[gp]*ss1*(1.0f+0.15f*cu);
    float ta = tanhf(theta[gp])*PI_F;
    float dxv=cosf(ta), dyv=sinf(ta);
    float car[8];
    #pragma unroll
    for(int ci=0;ci<8;ci++) car[ci]=carrier[((size_t)((b<<3)+ci)<<12)+p];
    #pragma unroll
    for(int co=0;co<8;co++){
        const float* w=&wl[co*12];
        float t = w[8] + w[9]*dxv + w[10]*dyv + w[11]*cu;
        #pragma unroll
        for(int ci=0;ci<8;ci++) t += w[ci]*car[ci];
        h[((size_t)((b<<3)+co)<<12)+p] = gelu_f(bl[co] + ssv*t);
    }
}

// ---------------- K8: pm2 1x1 conv 8->768 -> out (96 MB write) ----------------
// grid (32 pixel-chunks, 24 co-groups) x 256 threads, 32 co per group, float4 px
__global__ void k_pm2(const float* __restrict__ h, const float* __restrict__ w4,
                      const float* __restrict__ b4, float* __restrict__ out){
    int chunk=blockIdx.x; // 0..31
    int cg=blockIdx.y;    // 0..23
    int tid=threadIdx.x;
    int b=chunk>>2;
    int q0=((chunk&3)<<8)+tid;  // f4 index within batch plane
    const float4* h4=(const float4*)h;
    float4 hv[8];
    #pragma unroll
    for(int ci=0;ci<8;ci++) hv[ci]=h4[((size_t)((b<<3)+ci)<<10)+q0];
    float4* o4=(float4*)out;
    for(int k=0;k<32;k++){
        int co=cg*32+k;
        float bb=b4[co];
        float4 o=make_float4(bb,bb,bb,bb);
        #pragma unroll
        for(int ci=0;ci<8;ci++){
            float wv=w4[co*8+ci];
            o.x+=wv*hv[ci].x; o.y+=wv*hv[ci].y; o.z+=wv*hv[ci].z; o.w+=wv*hv[ci].w;
        }
        o4[(size_t)(b*768+co)*1024 + q0]=o;
    }
}

extern "C" void kernel_launch(void* const* d_in, const int* in_sizes, int n_in,
                              void* d_out, int out_size, void* d_ws, size_t ws_size,
                              hipStream_t stream) {
    const float* fm     =(const float*)d_in[0];
    const float* theta  =(const float*)d_in[1];
    const float* length =(const float*)d_in[2];
    const float* width  =(const float*)d_in[3];
    const float* curv   =(const float*)d_in[4];
    const float* alpha  =(const float*)d_in[5];
    const float* objn   =(const float*)d_in[6];
    const float* plog   =(const float*)d_in[7];
    const float* fp1w   =(const float*)d_in[8];
    const float* fp1b   =(const float*)d_in[9];
    const float* fp2w   =(const float*)d_in[10];
    const float* fp2b   =(const float*)d_in[11];
    const float* pm1w   =(const float*)d_in[12];
    const float* pm1b   =(const float*)d_in[13];
    const float* pm2w   =(const float*)d_in[14];
    const float* pm2b   =(const float*)d_in[15];
    const float* pdelta =(const float*)d_in[16];

    // pick channel-group count by available workspace (constant across calls)
    size_t rest = 262144 + 262144 + 32768 + 32768 + 32768 + 64 + 32768 + 32768 + 262144;
    int G = (ws_size >= ((size_t)16*262144 + rest)*sizeof(float)) ? 16 : 8;
    int Cg = 768/G;

    float* ws=(float*)d_ws;
    float* part    = ws;                         // G*262144
    float* t1      = part + (size_t)G*262144;    // 262144
    float* carrier = t1 + 262144;                // 262144
    float* cm      = carrier + 262144;           // 32768
    float* absc    = cm + 32768;                 // 32768
    float* csraw   = absc + 32768;               // 32768
    float* red     = csraw + 32768;              // 64
    float* sg      = red + 64;                   // 32768
    float* ss0     = sg + 32768;                 // 32768
    float* h       = ss0 + 32768;                // 262144
    float* out     = (float*)d_out;

    k_conv1 <<<dim3(32,G), 256, 0, stream>>>(fm, fp1w, part, Cg);
    k_comb1 <<<256, 256, 0, stream>>>(part, fp1b, t1, G);
    k_conv2 <<<128, 256, 0, stream>>>(t1, fp2w, fp2b, carrier, cm, absc);
    k_resp  <<<128, 256, 0, stream>>>(cm, pdelta, theta, length, width, plog, ss0, csraw);
    k_reduce<<<8, 256, 0, stream>>>(csraw, absc, red);
    k_gate  <<<8, 1024, 0, stream>>>(csraw, absc, objn, alpha, red, sg);
    k_h     <<<128, 256, 0, stream>>>(ss0, sg, theta, curv, carrier, pm1w, pm1b, h);
    k_pm2   <<<dim3(32,24), 256, 0, stream>>>(h, pm2w, pm2b, out);
}

// Round 4
// 350.974 us; speedup vs baseline: 1.4642x; 1.1367x over previous
//
#include <hip/hip_runtime.h>
#include <math.h>

#define PI_F 3.14159265358979323846f

__device__ __forceinline__ float gelu_f(float x){ return 0.5f*x*(1.0f+erff(x*0.7071067811865475f)); }
__device__ __forceinline__ float sigm_f(float x){ return 1.0f/(1.0f+expf(-x)); }

// B=8, H=W=64, HW=4096, NP=32768, FC=768, RC=8, P=8, K=9, G=8 channel groups

// ---------------- K1: fp1 1x1 conv 768->8, channel-split partials ----------------
__global__ void __launch_bounds__(256) k_conv1(const float* __restrict__ fm,
                        const float* __restrict__ w1, float* __restrict__ part){
    int chunk = blockIdx.x;   // 0..31
    int g = blockIdx.y;       // 0..7 (96 ch each)
    int tid = threadIdx.x;
    __shared__ float wl[96*8];
    for (int i=tid;i<96*8;i+=256){ int c=i>>3, co=i&7; wl[i]=w1[co*768 + g*96 + c]; }
    __syncthreads();
    int b = chunk>>2;
    int q0 = ((chunk&3)<<8) + tid;   // f4 offset within batch plane (0..1023)
    const float4* fm4 = (const float4*)fm;
    float4 acc[8];
    #pragma unroll
    for(int co=0;co<8;co++) acc[co]=make_float4(0.f,0.f,0.f,0.f);
    int basec = b*768 + g*96;
    for(int c=0;c<96;c++){
        float4 x = fm4[(size_t)(basec+c)*1024 + q0];
        #pragma unroll
        for(int co=0;co<8;co++){
            float wv = wl[(c<<3)+co];
            acc[co].x += wv*x.x; acc[co].y += wv*x.y; acc[co].z += wv*x.z; acc[co].w += wv*x.w;
        }
    }
    float4* p4 = (float4*)part;
    int gq = (b<<10) + q0;
    #pragma unroll
    for(int co=0;co<8;co++) p4[(size_t)(g*8+co)*8192 + gq] = acc[co];
}

// ---------------- K2 (k_mid): comb1 + conv2 + chp + 9x9 resp + top2 fused ----------------
// grid 256: block = (b 0..7, band 0..31), band = 2 output rows, y0 = band*2
__global__ void __launch_bounds__(256) k_mid(const float* __restrict__ part,
    const float* __restrict__ pd, const float* __restrict__ theta,
    const float* __restrict__ length, const float* __restrict__ width,
    const float* __restrict__ plog, const float* __restrict__ b1,
    const float* __restrict__ w2, const float* __restrict__ b2,
    float* __restrict__ carrier, float* __restrict__ absc,
    float* __restrict__ csraw, float* __restrict__ ss0, float* __restrict__ bpart){

    __shared__ float t1T[8][14*64];   // t1 rows y0-6..y0+7, 28 KB
    __shared__ float cmT[12*64];      // cm rows y0-5..y0+6
    __shared__ float chpT[10*64];     // chp rows y0-4..y0+5
    __shared__ float ridge[648];
    __shared__ float kl[648];
    __shared__ float w2s[576];
    __shared__ float pmS[8], pdenS[8];
    __shared__ float rS[256], rCmn[256], rCmx[256], rAmn[256], rAmx[256];

    int tid = threadIdx.x;
    int bl = blockIdx.x;
    int b = bl>>5, band = bl&31, y0 = band<<1;

    // ---- stage A: weights, ridge bank, t1 tile (sum of 8 partials + bias + gelu)
    for(int i=tid;i<576;i+=256) w2s[i]=w2[i];
    for(int t=tid;t<648;t+=256){
        int p=t/81, idx=t-p*81;
        int i=idx/9, j=idx-i*9;
        float ay=-1.f+0.25f*(float)i;
        float ax=-1.f+0.25f*(float)j;
        float ang=2.f*PI_F*(float)p*0.125f;
        const float Ls[3]={0.45f,0.75f,1.05f};
        const float Ws[3]={0.14f,0.20f,0.28f};
        float L=Ls[p%3], Wd=Ws[(p/3)%3];
        float cs=cosf(ang), sn=sinf(ang);
        float xr=ax*cs+ay*sn;
        float yr=-ax*sn+ay*cs;
        float tp=1.f-fminf(fabsf(xr)/L,1.f);
        float taper=powf(tp,1.5f);
        float core=expf(-0.5f*((xr/L)*(xr/L)+(yr/Wd)*(yr/Wd)));
        ridge[t]=taper*core*fmaxf(1.f-(yr/Wd)*(yr/Wd),0.f);
    }
    for(int co=0;co<8;co++){
        float bb = b1[co];
        for(int j=tid;j<896;j+=256){
            int r=j>>6, x=j&63;
            int gy=y0-6+r;
            float v=0.f;
            if(gy>=0 && gy<64){
                int px=(b<<12)+(gy<<6)+x;
                float s=0.f;
                #pragma unroll
                for(int g=0;g<8;g++) s += part[(size_t)((g<<3)+co)*32768 + px];
                v = gelu_f(s+bb);
            }
            t1T[co][j]=v;
        }
    }
    __syncthreads();

    // ---- stage B: bank mean / abs-sum (32 lanes per prototype)
    {
        int p=tid>>5, k=tid&31;
        float s=0.f;
        for(int e=k;e<81;e+=32) s+=ridge[p*81+e];
        for(int off=16;off>0;off>>=1) s+=__shfl_down(s,off,32);
        if(k==0) pmS[p]=s*(1.f/81.f);
    }
    __syncthreads();
    {
        int p=tid>>5, k=tid&31;
        float m=pmS[p];
        float s=0.f;
        for(int e=k;e<81;e+=32) s+=fabsf(ridge[p*81+e]-m);
        for(int off=16;off>0;off>>=1) s+=__shfl_down(s,off,32);
        if(k==0) pdenS[p]=fmaxf(s,1e-6f);
    }
    __syncthreads();

    // ---- stage C: kl + conv2 (cm rows, carrier/absc central rows)
    for(int t=tid;t<648;t+=256){
        int p=t/81;
        kl[t]=(ridge[t]-pmS[p])/pdenS[p]+0.05f*pd[t];
    }
    float aS=0.f, aMn=1e30f, aMx=-1e30f;
    {
        float b2r[8];
        #pragma unroll
        for(int co=0;co<8;co++) b2r[co]=b2[co];
        for(int j=tid;j<768;j+=256){
            int rc=j>>6, x=j&63;
            int gy=y0-5+rc;
            float cmv=0.f;
            if(gy>=0 && gy<64){
                float acc[8];
                #pragma unroll
                for(int co=0;co<8;co++) acc[co]=b2r[co];
                for(int ci=0;ci<8;ci++){
                    #pragma unroll
                    for(int dy=-1;dy<=1;dy++){
                        int tr=rc+1+dy;
                        #pragma unroll
                        for(int dx=-1;dx<=1;dx++){
                            int xx=x+dx;
                            float v=(xx>=0&&xx<64)?t1T[ci][tr*64+xx]:0.f;
                            int ti=(dy+1)*3+(dx+1);
                            #pragma unroll
                            for(int co=0;co<8;co++) acc[co]+=v*w2s[(co*8+ci)*9+ti];
                        }
                    }
                }
                float s=0.f, sa=0.f;
                bool central = (rc==5)||(rc==6);
                #pragma unroll
                for(int co=0;co<8;co++){
                    float cv=gelu_f(acc[co]);
                    if(central) carrier[((size_t)((b<<3)+co)<<12)+(gy<<6)+x]=cv;
                    s+=cv; sa+=fabsf(cv);
                }
                cmv=s*0.125f;
                if(central){
                    float av=sa*0.125f;
                    absc[(b<<12)+(gy<<6)+x]=av;
                    aS+=av; aMn=fminf(aMn,av); aMx=fmaxf(aMx,av);
                }
            }
            cmT[j]=cmv;
        }
    }
    __syncthreads();

    // ---- stage D: chp tile
    for(int j=tid;j<640;j+=256){
        int rh=j>>6, x=j&63;
        int gy=y0-4+rh;
        float v=0.f;
        if(gy>=0 && gy<64){
            float s=0.f;
            #pragma unroll
            for(int dy=-1;dy<=1;dy++){
                int cr=rh+1+dy;
                #pragma unroll
                for(int dx=-1;dx<=1;dx++){
                    int xx=x+dx;
                    if(xx>=0&&xx<64) s+=cmT[cr*64+xx];
                }
            }
            v=cmT[(rh+1)*64+x]-s*(1.f/9.f);
        }
        chpT[j]=v;
    }
    __syncthreads();

    // ---- stage E: 9x9 bank conv + csraw + top2 softmax (threads 0..127)
    float cMn=1e30f, cMx=-1e30f;
    if(tid<128){
        int ly=tid>>6, x=tid&63;
        int gy=y0+ly;
        int gp=(b<<12)+(gy<<6)+x;
        float acc[8];
        #pragma unroll
        for(int q=0;q<8;q++) acc[q]=0.f;
        float cs=0.f;
        for(int dy=-4;dy<=4;dy++){
            int lr=ly+dy+4;
            for(int dx=-4;dx<=4;dx++){
                int xx=x+dx;
                float v=(xx>=0&&xx<64)?chpT[lr*64+xx]:0.f;
                int ti=(dy+4)*9+(dx+4);
                #pragma unroll
                for(int q=0;q<8;q++) acc[q]+=v*kl[q*81+ti];
                if(dy>=-1&&dy<=1&&dx>=-1&&dx<=1) cs+=fabsf(v);
            }
        }
        float csv=cs*(1.f/9.f);
        csraw[gp]=csv;
        cMn=csv; cMx=csv;

        float ta=tanhf(theta[gp])*PI_F;
        float lv=sigm_f(length[gp])*0.85f+0.25f;
        float wv=sigm_f(width[gp])*0.22f+0.08f;
        const float Ls[3]={0.45f,0.75f,1.05f};
        const float Ws[3]={0.14f,0.20f,0.28f};
        int pp=(gy<<6)+x;
        float m1=-1e30f,m2=-1e30f; float r1v=0.f,r2v=0.f;
        #pragma unroll
        for(int q=0;q<8;q++){
            float ang=2.f*PI_F*(float)q*0.125f;
            float la=Ls[q%3], wa=Ws[(q/3)%3];
            float bias=plog[((size_t)((b<<3)+q)<<12)+pp]
                     +1.25f*cosf(ta-ang)
                     -(lv-la)*(lv-la)*(1.f/0.08f)
                     -(wv-wa)*(wv-wa)*(1.f/0.01f);
            if(bias>m1){m2=m1;r2v=r1v;m1=bias;r1v=acc[q];}
            else if(bias>m2){m2=bias;r2v=acc[q];}
        }
        float e2=expf(m2-m1);
        float inv=1.0f/(1.0f+e2);
        ss0[gp]=r1v*inv + r2v*e2*inv;
    }

    // ---- stage F: block partial reductions -> bpart
    rS[tid]=aS; rCmn[tid]=cMn; rCmx[tid]=cMx; rAmn[tid]=aMn; rAmx[tid]=aMx;
    __syncthreads();
    for(int st=128;st>0;st>>=1){
        if(tid<st){
            rS[tid]+=rS[tid+st];
            rCmn[tid]=fminf(rCmn[tid],rCmn[tid+st]);
            rCmx[tid]=fmaxf(rCmx[tid],rCmx[tid+st]);
            rAmn[tid]=fminf(rAmn[tid],rAmn[tid+st]);
            rAmx[tid]=fmaxf(rAmx[tid],rAmx[tid+st]);
        }
        __syncthreads();
    }
    if(tid==0){
        bpart[bl*8+0]=rS[0];
        bpart[bl*8+1]=rCmn[0];
        bpart[bl*8+2]=rCmx[0];
        bpart[bl*8+3]=rAmn[0];
        bpart[bl*8+4]=rAmx[0];
    }
}

// ---------------- K3 (k_gate): partial-reduce + full gate pipeline in LDS ----------------
__global__ void __launch_bounds__(1024) k_gate(const float* __restrict__ csraw,
    const float* __restrict__ absc, const float* __restrict__ objn,
    const float* __restrict__ alpha, const float* __restrict__ bpart,
    float* __restrict__ sg){
    __shared__ float A[4096], Bs[4096], Cs[4096];
    __shared__ float red5[5];
    int b=blockIdx.x, tid=threadIdx.x;
    if(tid==0){
        float sm=0.f, cmn=1e30f, cmx=-1e30f, amn=1e30f, amx=-1e30f;
        for(int j=0;j<32;j++){
            const float* bp=&bpart[(b*32+j)*8];
            sm+=bp[0];
            cmn=fminf(cmn,bp[1]); cmx=fmaxf(cmx,bp[2]);
            amn=fminf(amn,bp[3]); amx=fmaxf(amx,bp[4]);
        }
        float den=fmaxf(sm*(1.0f/4096.0f),1e-6f);
        red5[0]=den; red5[1]=cmn; red5[2]=cmx; red5[3]=amn/den; red5[4]=amx/den;
    }
    __syncthreads();
    float den=red5[0], cmn=red5[1], cmx=red5[2], dmn=red5[3], dmx=red5[4];
    float cinv = 1.0f/fmaxf(cmx-cmn,1e-6f);
    float dinv = 1.0f/fmaxf(dmx-dmn,1e-6f);
    for(int k=0;k<4;k++){
        int p=tid+k*1024;
        float cs=(csraw[(b<<12)+p]-cmn)*cinv;
        float d = absc[(b<<12)+p]/den;
        float ds=(d-dmn)*dinv;
        float ev = 0.65f*cs + 0.35f*ds;
        A[p]=ev;
        Bs[p]=sigm_f((ev-0.2f)*(1.0f/0.08f));
    }
    __syncthreads();
    for(int k=0;k<4;k++){
        int p=tid+k*1024; int y=p>>6,x=p&63;
        float m=-1e30f;
        for(int dy=-2;dy<=2;dy++){int yy=y+dy; if(yy<0||yy>=64)continue;
            for(int dx=-2;dx<=2;dx++){int xx=x+dx; if(xx<0||xx>=64)continue;
                m=fmaxf(m,Bs[(yy<<6)+xx]);}}
        Cs[p]=m;
    }
    __syncthreads();
    for(int k=0;k<4;k++){
        int p=tid+k*1024; int y=p>>6,x=p&63;
        float m=1.f;
        for(int dy=-2;dy<=2;dy++){int yy=y+dy; if(yy<0||yy>=64)continue;
            for(int dx=-2;dx<=2;dx++){int xx=x+dx; if(xx<0||xx>=64)continue;
                if (A[(yy<<6)+xx] < 0.2f) m=0.f;}}
        Bs[p]=m;
    }
    __syncthreads();
    for(int k=0;k<4;k++){
        int p=tid+k*1024; int y=p>>6,x=p&63;
        float m=-1e30f;
        for(int dy=-2;dy<=2;dy++){int yy=y+dy; if(yy<0||yy>=64)continue;
            for(int dx=-2;dx<=2;dx++){int xx=x+dx; if(xx<0||xx>=64)continue;
                m=fmaxf(m,Bs[(yy<<6)+xx]);}}
        A[p]=m;
    }
    __syncthreads();
    for(int k=0;k<4;k++){
        int p=tid+k*1024; int y=p>>6,x=p&63;
        float m=-1e30f;
        for(int dy=-2;dy<=2;dy++){int yy=y+dy; if(yy<0||yy>=64)continue;
            for(int dx=-2;dx<=2;dx++){int xx=x+dx; if(xx<0||xx>=64)continue;
                m=fmaxf(m,A[(yy<<6)+xx]);}}
        Bs[p]=m;
    }
    __syncthreads();
    for(int k=0;k<4;k++){
        int p=tid+k*1024;
        A[p]=sigm_f(objn[(b<<12)+p]);
    }
    __syncthreads();
    for(int k=0;k<4;k++){
        int p=tid+k*1024; int y=p>>6,x=p&63;
        float s=0.f;
        for(int dy=-1;dy<=1;dy++){int yy=y+dy; if(yy<0||yy>=64)continue;
            for(int dx=-1;dx<=1;dx++){int xx=x+dx; if(xx<0||xx>=64)continue;
                s += A[(yy<<6)+xx];}}
        float blob = s*(1.0f/9.0f);
        float gate = Cs[p]*Bs[p];
        float d = absc[(b<<12)+p]/den;
        float sgv = sigm_f(alpha[(b<<12)+p]) * blob * gate * (0.7f+0.3f*fminf(fmaxf(d,0.f),2.f));
        sg[(b<<12)+p] = sgv;
    }
}

// ---------------- K4 (k_out): k_h + pm2 fused ----------------
// grid 256 x 256: block handles 32 f4px (128 px); phase1 h->LDS, phase2 8->768 expand
__global__ void __launch_bounds__(256) k_out(const float* __restrict__ ss0,
    const float* __restrict__ sg, const float* __restrict__ theta,
    const float* __restrict__ curv, const float* __restrict__ carrier,
    const float* __restrict__ w3, const float* __restrict__ b3,
    const float* __restrict__ w4, const float* __restrict__ b4,
    float* __restrict__ out){
    __shared__ float hS[8][128];     // 4 KB
    __shared__ float w4s[768*8];     // 24 KB
    __shared__ float b4s[768];
    __shared__ float wl[96];
    __shared__ float bl3[8];
    int tid=threadIdx.x;
    int bln=blockIdx.x;
    for(int i=tid;i<6144;i+=256) w4s[i]=w4[i];
    for(int i=tid;i<768;i+=256) b4s[i]=b4[i];
    if(tid<96) wl[tid]=w3[tid];
    if(tid<8) bl3[tid]=b3[tid];
    __syncthreads();   // wl/bl3 written by waves 0-1, read cross-wave below

    if(tid<128){
        int gp=bln*128+tid;
        int b=gp>>12, p=gp&4095, y=p>>6, x=p&63;
        const float* base = ss0 + (b<<12);
        float s=0.f;
        for(int dy=-1;dy<=1;dy++){int yy=y+dy; if(yy<0||yy>=64)continue;
            for(int dx=-1;dx<=1;dx++){int xx=x+dx;if(xx<0||xx>=64)continue;
                s+=base[(yy<<6)+xx];}}
        float ss1 = base[p]-s*(1.0f/9.0f);
        float cu = tanhf(curv[gp]);
        float ssv = sg[gp]*ss1*(1.0f+0.15f*cu);
        float ta = tanhf(theta[gp])*PI_F;
        float dxv=cosf(ta), dyv=sinf(ta);
        float car[8];
        #pragma unroll
        for(int ci=0;ci<8;ci++) car[ci]=carrier[((size_t)((b<<3)+ci)<<12)+p];
        #pragma unroll
        for(int co=0;co<8;co++){
            const float* w=&wl[co*12];
            float t = w[8] + w[9]*dxv + w[10]*dyv + w[11]*cu;
            #pragma unroll
            for(int ci=0;ci<8;ci++) t += w[ci]*car[ci];
            hS[co][tid] = gelu_f(bl3[co] + ssv*t);
        }
    }
    __syncthreads();

    int px4 = tid&31;          // f4 px within block
    int cg = tid>>5;           // 0..7, 96 co each
    int q0 = bln*32 + px4;     // GLOBAL f4 index (0..8191)
    int b = q0>>10;
    int ql = q0 & 1023;        // within-batch f4 index  (round-3 bug: used q0 here -> OOB)
    float4 hv[8];
    #pragma unroll
    for(int ci=0;ci<8;ci++) hv[ci]=*(const float4*)&hS[ci][px4<<2];
    float4* o4=(float4*)out;
    for(int k=0;k<96;k++){
        int co=cg*96+k;
        float bb=b4s[co];
        float4 o=make_float4(bb,bb,bb,bb);
        const float* w=&w4s[co<<3];
        #pragma unroll
        for(int ci=0;ci<8;ci++){
            float wv=w[ci];
            o.x+=wv*hv[ci].x; o.y+=wv*hv[ci].y; o.z+=wv*hv[ci].z; o.w+=wv*hv[ci].w;
        }
        o4[(size_t)(b*768+co)*1024 + ql]=o;
    }
}

extern "C" void kernel_launch(void* const* d_in, const int* in_sizes, int n_in,
                              void* d_out, int out_size, void* d_ws, size_t ws_size,
                              hipStream_t stream) {
    const float* fm     =(const float*)d_in[0];
    const float* theta  =(const float*)d_in[1];
    const float* length =(const float*)d_in[2];
    const float* width  =(const float*)d_in[3];
    const float* curv   =(const float*)d_in[4];
    const float* alpha  =(const float*)d_in[5];
    const float* objn   =(const float*)d_in[6];
    const float* plog   =(const float*)d_in[7];
    const float* fp1w   =(const float*)d_in[8];
    const float* fp1b   =(const float*)d_in[9];
    const float* fp2w   =(const float*)d_in[10];
    const float* fp2b   =(const float*)d_in[11];
    const float* pm1w   =(const float*)d_in[12];
    const float* pm1b   =(const float*)d_in[13];
    const float* pm2w   =(const float*)d_in[14];
    const float* pm2b   =(const float*)d_in[15];
    const float* pdelta =(const float*)d_in[16];

    float* ws=(float*)d_ws;
    float* part    = ws;                  // 8*8*32768 = 2097152
    float* carrier = part + 2097152;      // 262144
    float* absc    = carrier + 262144;    // 32768
    float* csraw   = absc + 32768;        // 32768
    float* ss0     = csraw + 32768;       // 32768
    float* sg      = ss0 + 32768;         // 32768
    float* bpart   = sg + 32768;          // 2048
    float* out     = (float*)d_out;

    k_conv1<<<dim3(32,8), 256, 0, stream>>>(fm, fp1w, part);
    k_mid  <<<256, 256, 0, stream>>>(part, pdelta, theta, length, width, plog,
                                     fp1b, fp2w, fp2b, carrier, absc, csraw, ss0, bpart);
    k_gate <<<8, 1024, 0, stream>>>(csraw, absc, objn, alpha, bpart, sg);
    k_out  <<<256, 256, 0, stream>>>(ss0, sg, theta, curv, carrier,
                                     pm1w, pm1b, pm2w, pm2b, out);
}